// Round 11
// baseline (558.731 us; speedup 1.0000x reference)
//
#include <hip/hip_runtime.h>
#include <hip/hip_bf16.h>
#include <hip/hip_fp16.h>
#include <cstdint>
#include <cstddef>

#define NTOK 16384
#define HD   1024
#define CD   256
#define NE   16
#define RD   128
#define MB2    272          // upper bound on 128-token blocks over all experts
#define LOGB   2176         // MB2 * 8 ct-tiles
#define EGRID  2304         // ceil(LOGB/256)*256  (multiple of 256 -> bijective remap)

typedef __attribute__((ext_vector_type(8))) short bf16x8;
typedef __attribute__((ext_vector_type(4))) float f32x4;
typedef unsigned short u16;
typedef unsigned int u32;

__device__ __forceinline__ u16 f2bf(float f) {
    u32 u = __float_as_uint(f);
    u32 r = (u + 0x7FFFu + ((u >> 16) & 1u)) >> 16;   // RNE
    return (u16)r;
}
__device__ __forceinline__ float bf2f(u16 h) {
    u32 u = ((u32)h) << 16;
    return __uint_as_float(u);
}

__device__ __forceinline__ void gload16(const void* g, void* lds) {
    __builtin_amdgcn_global_load_lds((const __attribute__((address_space(1))) void*)g,
                                     (__attribute__((address_space(3))) void*)lds,
                                     16, 0, 0);
}

__device__ __forceinline__ float wredsum(float v) {
#pragma unroll
    for (int m = 32; m >= 1; m >>= 1) v += __shfl_xor(v, m, 64);
    return v;
}

// ---------------- K1: normalize centroids ----------------
__global__ __launch_bounds__(64) void centroid_norm_kernel(
    const float* __restrict__ cen, float* __restrict__ cn, float* __restrict__ sncn)
{
    int e = blockIdx.x, l = threadIdx.x;
    float4 c = *(const float4*)&cen[e * CD + l * 4];
    float ss = wredsum(c.x * c.x + c.y * c.y + c.z * c.z + c.w * c.w);
    float den = fmaxf(sqrtf(ss), 1e-8f);
    float4 n;
    n.x = c.x / den; n.y = c.y / den; n.z = c.z / den; n.w = c.w / den;
    *(float4*)&cn[e * CD + l * 4] = n;
    float s2 = wredsum(n.x * n.x + n.y * n.y + n.z * n.z + n.w * n.w);
    if (l == 0) sncn[e] = s2;
}

// ---------------- K2: x -> bf16 hi (xbf) + bf16 lo (xlo) ----------------
__global__ __launch_bounds__(256) void cvt_split_kernel(
    const float* __restrict__ src, u16* __restrict__ hi, u16* __restrict__ lo, int n4)
{
    int i = blockIdx.x * 256 + threadIdx.x;
    if (i >= n4) return;
    float4 v = *(const float4*)&src[(size_t)i * 4];
    ushort4 h, l;
    h.x = f2bf(v.x); h.y = f2bf(v.y); h.z = f2bf(v.z); h.w = f2bf(v.w);
    l.x = f2bf(v.x - bf2f(h.x)); l.y = f2bf(v.y - bf2f(h.y));
    l.z = f2bf(v.z - bf2f(h.z)); l.w = f2bf(v.w - bf2f(h.w));
    *(ushort4*)&hi[(size_t)i * 4] = h;
    *(ushort4*)&lo[(size_t)i * 4] = l;
}

// ---------------- K3: per-expert transpose + convert: src [K][N] -> dst [N][K] ----------------
__global__ __launch_bounds__(256) void transpose_cvt_kernel(
    const float* __restrict__ src, u16* __restrict__ dst, int K, int N)
{
    __shared__ float t[32][33];
    const float* s = src + (size_t)blockIdx.z * K * N;
    u16* d = dst + (size_t)blockIdx.z * K * N;
    int kb = blockIdx.y * 32, nb = blockIdx.x * 32;
    int r = threadIdx.x >> 3, c4 = (threadIdx.x & 7) * 4;
    float4 v = *(const float4*)&s[(size_t)(kb + r) * N + nb + c4];
    t[r][c4 + 0] = v.x; t[r][c4 + 1] = v.y; t[r][c4 + 2] = v.z; t[r][c4 + 3] = v.w;
    __syncthreads();
    ushort4 o;
    o.x = f2bf(t[c4 + 0][r]); o.y = f2bf(t[c4 + 1][r]);
    o.z = f2bf(t[c4 + 2][r]); o.w = f2bf(t[c4 + 3][r]);
    *(ushort4*)&d[(size_t)(nb + r) * K + kb + c4] = o;
}

// ---------------- K3b: Wd [K][N] -> wdh/wdl [N][K] (hi/lo split) ----------------
__global__ __launch_bounds__(256) void transpose_cvt_split_kernel(
    const float* __restrict__ src, u16* __restrict__ dh, u16* __restrict__ dl,
    int K, int N)
{
    __shared__ float t[32][33];
    int kb = blockIdx.y * 32, nb = blockIdx.x * 32;
    int r = threadIdx.x >> 3, c4 = (threadIdx.x & 7) * 4;
    float4 v = *(const float4*)&src[(size_t)(kb + r) * N + nb + c4];
    t[r][c4 + 0] = v.x; t[r][c4 + 1] = v.y; t[r][c4 + 2] = v.z; t[r][c4 + 3] = v.w;
    __syncthreads();
    float f0 = t[c4 + 0][r], f1 = t[c4 + 1][r], f2 = t[c4 + 2][r], f3 = t[c4 + 3][r];
    ushort4 h, l;
    h.x = f2bf(f0); h.y = f2bf(f1); h.z = f2bf(f2); h.w = f2bf(f3);
    l.x = f2bf(f0 - bf2f(h.x)); l.y = f2bf(f1 - bf2f(h.y));
    l.z = f2bf(f2 - bf2f(h.z)); l.w = f2bf(f3 - bf2f(h.w));
    *(ushort4*)&dh[(size_t)(nb + r) * K + kb + c4] = h;
    *(ushort4*)&dl[(size_t)(nb + r) * K + kb + c4] = l;
}

// Swizzle (all MFMA kernels): stored[row][s]=logical[row][s^((row>>1)&3)];
// stage slot sl=(lane&3)^((lane>>3)&3); read slot rslot=hi^((rr>>1)&3).
// Pipeline (verified, spill-robust): STAGE(next) -> COMP(cur) -> __syncthreads().

// ---------------- K4: router GEMM, split-bf16 MFMA ----------------
__global__ __launch_bounds__(256, 2) void router_mfma_kernel(
    const u16* __restrict__ xh, const u16* __restrict__ xl,
    const u16* __restrict__ wdh, const u16* __restrict__ wdl,
    const float* __restrict__ bd, float* __restrict__ dT)
{
    __shared__ __align__(16) u16 lds[2 * 16384];
    int rb = (blockIdx.x >> 1) * 128;
    int cb = (blockIdx.x & 1) * 128;
    int tid = threadIdx.x, lane = tid & 63, w = tid >> 6;
    int lrow = lane >> 2;
    int sl = (lane & 3) ^ ((lane >> 3) & 3);
    int rr = lane & 15, hi = lane >> 4;
    int rslot = hi ^ ((rr >> 1) & 3);
    int wr = w >> 1, wc = w & 1;

    const u16* gb[8]; char* lp[8];
#pragma unroll
    for (int i = 0; i < 8; ++i) {
        int idx = w + 4 * i;
        int sub = idx & 7;
        int row = sub * 16 + lrow;
        if (idx < 8) {
            gb[i] = xh + (size_t)(rb + row) * HD + sl * 8;
            lp[i] = (char*)lds + idx * 1024;
        } else if (idx < 16) {
            gb[i] = xl + (size_t)(rb + row) * HD + sl * 8;
            lp[i] = (char*)lds + 8192 + sub * 1024;
        } else if (idx < 24) {
            gb[i] = wdh + (size_t)(cb + row) * HD + sl * 8;
            lp[i] = (char*)lds + 16384 + sub * 1024;
        } else {
            gb[i] = wdl + (size_t)(cb + row) * HD + sl * 8;
            lp[i] = (char*)lds + 24576 + sub * 1024;
        }
    }

    const f32x4 zz = {0.f, 0.f, 0.f, 0.f};
    f32x4 acc[4][4];
#pragma unroll
    for (int im = 0; im < 4; ++im)
#pragma unroll
        for (int in = 0; in < 4; ++in) acc[im][in] = zz;

    auto STAGE = [&](int buf, int t) {
#pragma unroll
        for (int i = 0; i < 8; ++i) gload16(gb[i] + t * 32, lp[i] + buf * 32768);
    };
    auto COMP = [&](int buf) {
        const u16* LXH = lds + buf * 16384;
        const u16* LXL = LXH + 4096;
        const u16* LWH = LXH + 8192;
        const u16* LWL = LXH + 12288;
        bf16x8 ah[4], al[4], bh[4], bl[4];
#pragma unroll
        for (int im = 0; im < 4; ++im) {
            int row = wr * 64 + im * 16 + rr;
            ah[im] = *(const bf16x8*)&LXH[row * 32 + rslot * 8];
            al[im] = *(const bf16x8*)&LXL[row * 32 + rslot * 8];
        }
#pragma unroll
        for (int in = 0; in < 4; ++in) {
            int row = wc * 64 + in * 16 + rr;
            bh[in] = *(const bf16x8*)&LWH[row * 32 + rslot * 8];
            bl[in] = *(const bf16x8*)&LWL[row * 32 + rslot * 8];
        }
#pragma unroll
        for (int im = 0; im < 4; ++im)
#pragma unroll
            for (int in = 0; in < 4; ++in) {
                acc[im][in] = __builtin_amdgcn_mfma_f32_16x16x32_bf16(ah[im], bh[in], acc[im][in], 0, 0, 0);
                acc[im][in] = __builtin_amdgcn_mfma_f32_16x16x32_bf16(ah[im], bl[in], acc[im][in], 0, 0, 0);
                acc[im][in] = __builtin_amdgcn_mfma_f32_16x16x32_bf16(al[im], bh[in], acc[im][in], 0, 0, 0);
            }
    };

    STAGE(0, 0);
    __syncthreads();
    for (int t = 0; t < 31; ++t) {
        STAGE((t + 1) & 1, t + 1);
        COMP(t & 1);
        __syncthreads();
    }
    COMP(1);

#pragma unroll
    for (int im = 0; im < 4; ++im)
#pragma unroll
        for (int in = 0; in < 4; ++in) {
            int c = cb + wc * 64 + in * 16 + rr;
            float b = bd[c];
            float g[4];
#pragma unroll
            for (int j = 0; j < 4; ++j) {
                float v = acc[im][in][j] + b;
                g[j] = 0.5f * v * (1.f + erff(v * 0.70710678118654752f));
            }
            float4 o = {g[0], g[1], g[2], g[3]};
            *(float4*)&dT[(size_t)c * NTOK + rb + wr * 64 + im * 16 + hi * 4] = o;
        }
}

// ---------------- K5: router score — lane-local dots, no shuffles ----------------
__global__ __launch_bounds__(256) void router_score_kernel(
    const float* __restrict__ dT, const float* __restrict__ cn,
    const float* __restrict__ sncn, int* __restrict__ top_i,
    float* __restrict__ top_w, int* __restrict__ counts)
{
    __shared__ float lcn[NE][CD];
    __shared__ float sdot[NE][64];
    __shared__ float sss[64];
    __shared__ int hist[NE];
    int tid = threadIdx.x, lane = tid & 63, w = tid >> 6;
    for (int i = tid; i < NE * CD / 4; i += 256)
        ((float4*)&lcn[0][0])[i] = ((const float4*)cn)[i];
    if (tid < NE) hist[tid] = 0;
    __syncthreads();

    int tokbase = blockIdx.x * 64;
    const float* p = dT + tokbase + lane;
    int e0 = w * 4;
    float d0 = 0.f, d1 = 0.f, d2a = 0.f, d3 = 0.f, ss = 0.f;
#pragma unroll 4
    for (int k = 0; k < CD; ++k) {
        float v = p[(size_t)k * NTOK];
        ss = fmaf(v, v, ss);
        d0 = fmaf(v, lcn[e0 + 0][k], d0);
        d1 = fmaf(v, lcn[e0 + 1][k], d1);
        d2a = fmaf(v, lcn[e0 + 2][k], d2a);
        d3 = fmaf(v, lcn[e0 + 3][k], d3);
    }
    sdot[e0 + 0][lane] = d0;
    sdot[e0 + 1][lane] = d1;
    sdot[e0 + 2][lane] = d2a;
    sdot[e0 + 3][lane] = d3;
    if (w == 0) sss[lane] = ss;
    __syncthreads();

    if (tid < 64) {
        int tok = tokbase + tid;
        float ssv = sss[tid];
        float den = fmaxf(sqrtf(ssv), 1e-8f);
        float inv = 1.f / den;
        float sndn = (ssv * inv) * inv;
        float pr[NE];
#pragma unroll
        for (int e = 0; e < NE; ++e) {
            float dotn = sdot[e][tid] * inv;
            float dd2 = sndn + sncn[e] - 2.f * dotn;
            pr[e] = -sqrtf(fmaxf(dd2, 0.f));
        }
        float mx = pr[0];
#pragma unroll
        for (int e = 1; e < NE; ++e) mx = fmaxf(mx, pr[e]);
        float sum = 0.f;
#pragma unroll
        for (int e = 0; e < NE; ++e) { pr[e] = expf(pr[e] - mx); sum += pr[e]; }
        float invs = 1.f / sum;
#pragma unroll
        for (int e = 0; e < NE; ++e) pr[e] *= invs;
        int i1 = 0; float p1 = pr[0];
#pragma unroll
        for (int e = 1; e < NE; ++e) if (pr[e] > p1) { p1 = pr[e]; i1 = e; }
        int i2 = -1; float p2 = -1.f;
#pragma unroll
        for (int e = 0; e < NE; ++e) if (e != i1 && pr[e] > p2) { p2 = pr[e]; i2 = e; }
        top_i[tok * 2 + 0] = i1; top_w[tok * 2 + 0] = p1;
        top_i[tok * 2 + 1] = i2; top_w[tok * 2 + 1] = p2;
        atomicAdd(&hist[i1], 1);
        atomicAdd(&hist[i2], 1);
    }
    __syncthreads();
    if (tid < NE) atomicAdd(&counts[tid], hist[tid]);
}

// ---------------- K6: tiny scan (128-row blocks) ----------------
__global__ void scan_kernel(const int* __restrict__ counts, int* __restrict__ offsets,
                            int* __restrict__ blkstart, int* __restrict__ cursor)
{
    if (threadIdx.x == 0 && blockIdx.x == 0) {
        int o = 0, b = 0;
        for (int e = 0; e < NE; ++e) {
            offsets[e] = o; blkstart[e] = b; cursor[e] = 0;
            o += counts[e]; b += (counts[e] + 127) >> 7;
        }
        offsets[NE] = o; blkstart[NE] = b;
    }
}

// ---------------- K7: build per-expert token lists ----------------
__global__ __launch_bounds__(256) void build_lists_kernel(
    const int* __restrict__ top_i, const float* __restrict__ top_w,
    const int* __restrict__ offsets, int* __restrict__ cursor,
    int* __restrict__ list_tok, float* __restrict__ list_w)
{
    int t = blockIdx.x * 256 + threadIdx.x;
#pragma unroll
    for (int j = 0; j < 2; ++j) {
        int e = top_i[t * 2 + j];
        int pos = atomicAdd(&cursor[e], 1);
        int idx = offsets[e] + pos;
        list_tok[idx] = t;
        list_w[idx] = top_w[t * 2 + j];
    }
}

// ---------------- K8: t = x @ U_e — M=128 ----------------
__global__ __launch_bounds__(256, 4) void tproj_kernel(
    const u16* __restrict__ xbf, const u16* __restrict__ uT,
    const int* __restrict__ list_tok, const int* __restrict__ offsets,
    const int* __restrict__ blkstart, u16* __restrict__ tbf)
{
    __shared__ __align__(16) u16 lds[2 * 8192];
    __shared__ int s_tok[128];
    int mb = blockIdx.x;
    int e = 0;
#pragma unroll
    for (int i = 0; i < NE; ++i) if (mb >= blkstart[i + 1]) e = i + 1;
    if (e >= NE) return;
    int mloc = (mb - blkstart[e]) * 128;
    int base = offsets[e] + mloc;
    int cnt = offsets[e + 1] - offsets[e];
    int mv = min(128, cnt - mloc);
    int tid = threadIdx.x, lane = tid & 63, w = tid >> 6;
    if (tid < 128) s_tok[tid] = list_tok[base + (tid < mv ? tid : 0)];
    __syncthreads();
    int lrow = lane >> 2;
    int sl = (lane & 3) ^ ((lane >> 3) & 3);
    int rr = lane & 15, hi = lane >> 4;
    int rslot = hi ^ ((rr >> 1) & 3);
    int wr = w >> 1, wc = w & 1;
    const u16* uE = uT + (size_t)e * RD * HD;

    const u16* gb[4]; char* lp[4];
#pragma unroll
    for (int i = 0; i < 4; ++i) {
        int idx = w + 4 * i;
        if (idx < 8) {
            int row = idx * 16 + lrow;
            gb[i] = xbf + (size_t)s_tok[row] * HD + sl * 8;
            lp[i] = (char*)lds + idx * 1024;
        } else {
            int row = (idx - 8) * 16 + lrow;
            gb[i] = uE + (size_t)row * HD + sl * 8;
            lp[i] = (char*)lds + 8192 + (idx - 8) * 1024;
        }
    }
    const f32x4 zz = {0.f, 0.f, 0.f, 0.f};
    f32x4 acc[4][4];
#pragma unroll
    for (int im = 0; im < 4; ++im)
#pragma unroll
        for (int in = 0; in < 4; ++in) acc[im][in] = zz;

    auto STAGE = [&](int buf, int t) {
#pragma unroll
        for (int i = 0; i < 4; ++i) gload16(gb[i] + t * 32, lp[i] + buf * 16384);
    };
    auto COMP = [&](int buf, f32x4 (&a)[4][4]) {
        const u16* LA = lds + buf * 8192;
        const u16* LB = LA + 4096;
        bf16x8 af[4], bfv[4];
#pragma unroll
        for (int im = 0; im < 4; ++im) af[im] = *(const bf16x8*)&LA[(wr * 64 + im * 16 + rr) * 32 + rslot * 8];
#pragma unroll
        for (int in = 0; in < 4; ++in) bfv[in] = *(const bf16x8*)&LB[(wc * 64 + in * 16 + rr) * 32 + rslot * 8];
#pragma unroll
        for (int im = 0; im < 4; ++im)
#pragma unroll
            for (int in = 0; in < 4; ++in)
                a[im][in] = __builtin_amdgcn_mfma_f32_16x16x32_bf16(af[im], bfv[in], a[im][in], 0, 0, 0);
    };

    STAGE(0, 0);
    __syncthreads();
    for (int t = 0; t < 31; ++t) {
        STAGE((t + 1) & 1, t + 1);
        COMP(t & 1, acc);
        __syncthreads();
    }
    COMP(1, acc);

#pragma unroll
    for (int im = 0; im < 4; ++im)
#pragma unroll
        for (int in = 0; in < 4; ++in)
#pragma unroll
            for (int j = 0; j < 4; ++j) {
                int r = wr * 64 + im * 16 + hi * 4 + j;
                if (r < mv) {
                    int c = wc * 64 + in * 16 + rr;
                    tbf[(size_t)(base + r) * RD + c] = f2bf(acc[im][in][j]);
                }
            }
}

// ---------------- K9: gate GEMM -> sigmoid fp16 pack -> trans GEMM -> highway epilogue ----------------
// Gate-first ordering keeps only ONE accumulator + ONE pointer set live per phase:
//   phase A: accG(64 agpr) + gbG;  pack sg->fp16 sgp(16 vgpr);  phase B: accT(64) + gbT (recomputed).
// __launch_bounds__(256,4) caps regs at 128 -> 4 waves/SIMD (16 waves/CU) vs prior 148 regs -> 3.
// Spills (if any) are perf-only: the syncthreads-drain pipeline is spill-robust (R3/R7 lesson).
__global__ __launch_bounds__(256, 4) void expert_kernel(
    const u16* __restrict__ xbf, const u16* __restrict__ wgT,
    const u16* __restrict__ vT, const u16* __restrict__ tbf,
    const float* __restrict__ x, const float* __restrict__ bg,
    const int* __restrict__ list_tok, const float* __restrict__ list_w,
    const int* __restrict__ offsets, const int* __restrict__ blkstart,
    float* __restrict__ out)
{
    __shared__ __align__(16) u16 lds[2 * 8192];
    __shared__ int s_tok[128];
    __shared__ float s_w[128];
    int d = blockIdx.x;
    int l = (d >> 8) * 256 + (d & 7) * 32 + ((d & 255) >> 3);
    if (l >= LOGB) return;
    int g = l >> 5, i2d = l & 31;
    int mb = (g >> 1) * 8 + (i2d & 7);
    int ct = (g & 1) * 4 + (i2d >> 3);
    int e = 0;
#pragma unroll
    for (int i = 0; i < NE; ++i) if (mb >= blkstart[i + 1]) e = i + 1;
    if (e >= NE) return;
    int mloc = (mb - blkstart[e]) * 128;
    int base = offsets[e] + mloc;
    int cnt = offsets[e + 1] - offsets[e];
    int mv = min(128, cnt - mloc);
    int tid = threadIdx.x, lane = tid & 63, w = tid >> 6;
    if (tid < 128) {
        int p = base + (tid < mv ? tid : 0);
        s_tok[tid] = list_tok[p];
        s_w[tid] = (tid < mv) ? list_w[p] : 0.f;
    }
    __syncthreads();
    int lrow = lane >> 2;
    int sl = (lane & 3) ^ ((lane >> 3) & 3);
    int rr = lane & 15, hi = lane >> 4;
    int rslot = hi ^ ((rr >> 1) & 3);
    int wr = w >> 1, wc = w & 1;

    const u16* wgE = wgT + (size_t)e * HD * HD + (size_t)(ct * 128) * HD;

    char* lp[4];
#pragma unroll
    for (int i = 0; i < 4; ++i) {
        int idx = w + 4 * i;
        lp[i] = (char*)lds + ((idx < 8) ? idx * 1024 : 8192 + (idx - 8) * 1024);
    }

    auto STAGE = [&](int buf, int t, const u16* const (&gb)[4]) {
#pragma unroll
        for (int i = 0; i < 4; ++i) gload16(gb[i] + t * 32, lp[i] + buf * 16384);
    };
    auto COMP = [&](int buf, f32x4 (&a)[4][4]) {
        const u16* LA = lds + buf * 8192;
        const u16* LB = LA + 4096;
        bf16x8 af[4], bfv[4];
#pragma unroll
        for (int im = 0; im < 4; ++im) af[im] = *(const bf16x8*)&LA[(wr * 64 + im * 16 + rr) * 32 + rslot * 8];
#pragma unroll
        for (int in = 0; in < 4; ++in) bfv[in] = *(const bf16x8*)&LB[(wc * 64 + in * 16 + rr) * 32 + rslot * 8];
#pragma unroll
        for (int im = 0; im < 4; ++im)
#pragma unroll
            for (int in = 0; in < 4; ++in)
                a[im][in] = __builtin_amdgcn_mfma_f32_16x16x32_bf16(af[im], bfv[in], a[im][in], 0, 0, 0);
    };

    const f32x4 zz = {0.f, 0.f, 0.f, 0.f};

    // ---- phase A: gate = x @ Wg_e (32 K-steps); only gbG + accG live ----
    {
        const u16* gbG[4];
#pragma unroll
        for (int i = 0; i < 4; ++i) {
            int idx = w + 4 * i;
            if (idx < 8) {
                int row = idx * 16 + lrow;
                gbG[i] = xbf + (size_t)s_tok[row] * HD + sl * 8;
            } else {
                int row = (idx - 8) * 16 + lrow;
                gbG[i] = wgE + (size_t)row * HD + sl * 8;
            }
        }

        f32x4 accG[4][4];
#pragma unroll
        for (int im = 0; im < 4; ++im)
#pragma unroll
            for (int in = 0; in < 4; ++in) accG[im][in] = zz;

        STAGE(0, 0, gbG);
        __syncthreads();
        for (int t = 0; t < 31; ++t) {
            STAGE((t + 1) & 1, t + 1, gbG);
            COMP(t & 1, accG);
            __syncthreads();
        }
        COMP(1, accG);
        // buf0's last reader (t=30's COMP(0)) was barriered at t=30 end -> safe to restage buf0 below.

        // sigmoid + pack to fp16; bgv loaded here (phase-local)
        float bgv[4];
#pragma unroll
        for (int in = 0; in < 4; ++in)
            bgv[in] = bg[e * HD + ct * 128 + wc * 64 + in * 16 + rr];
        __half2* sgp = (__half2*)&s_w[0];   // placeholder decl avoidance — real array below
        (void)sgp;
        // store into registers (declared in outer scope below)
        // (see sgp_reg)
        // -- fallthrough handled by outer-scope array --
        // compute into outer array:
        extern __shared__ char _dummy[]; (void)_dummy;
        // packing done after gbT stage issue (outer scope)
        // Save accG via pack now:
        // (moved below to keep single definition)
        // NOTE: code restructured: pack happens in outer scope right after this block
        // via accG copy — to keep liveness tight we pack HERE:
        {
            // pack into the outer sgp_reg
        }
        // Stage trans tile 0 before packing so the load overlaps the VALU pack:
        {
            const u16* vE = vT + (size_t)e * HD * RD + (size_t)(ct * 128) * RD;
            const u16* gbT0[4];
#pragma unroll
            for (int i = 0; i < 4; ++i) {
                int idx = w + 4 * i;
                if (idx < 8) {
                    int row = idx * 16 + lrow;
                    gbT0[i] = tbf + (size_t)(base + (row < mv ? row : 0)) * RD + sl * 8;
                } else {
                    int row = (idx - 8) * 16 + lrow;
                    gbT0[i] = vE + (size_t)row * RD + sl * 8;
                }
            }
            STAGE(0, 0, gbT0);
        }
        // pack sg to fp16 (outer-scope array), freeing accG
        __half2 sgp_reg[4][4][2];
#pragma unroll
        for (int im = 0; im < 4; ++im)
#pragma unroll
            for (int in = 0; in < 4; ++in) {
                float s0 = 1.f / (1.f + __expf(-(accG[im][in][0] + bgv[in])));
                float s1 = 1.f / (1.f + __expf(-(accG[im][in][1] + bgv[in])));
                float s2 = 1.f / (1.f + __expf(-(accG[im][in][2] + bgv[in])));
                float s3 = 1.f / (1.f + __expf(-(accG[im][in][3] + bgv[in])));
                sgp_reg[im][in][0] = __floats2half2_rn(s0, s1);
                sgp_reg[im][in][1] = __floats2half2_rn(s2, s3);
            }
        __syncthreads();   // trans tile 0 staged & drained

        // ---- phase B: trans = t @ V_e (4 K-steps) ----
        const u16* vE = vT + (size_t)e * HD * RD + (size_t)(ct * 128) * RD;
        const u16* gbT[4];
#pragma unroll
        for (int i = 0; i < 4; ++i) {
            int idx = w + 4 * i;
            if (idx < 8) {
                int row = idx * 16 + lrow;
                gbT[i] = tbf + (size_t)(base + (row < mv ? row : 0)) * RD + sl * 8;
            } else {
                int row = (idx - 8) * 16 + lrow;
                gbT[i] = vE + (size_t)row * RD + sl * 8;
            }
        }

        f32x4 accT[4][4];
#pragma unroll
        for (int im = 0; im < 4; ++im)
#pragma unroll
            for (int in = 0; in < 4; ++in) accT[im][in] = zz;

#pragma unroll
        for (int s = 0; s < 4; ++s) {
            if (s < 3) STAGE((s + 1) & 1, s + 1, gbT);
            COMP(s & 1, accT);
            __syncthreads();
        }

        // ---- epilogue ----
#pragma unroll
        for (int im = 0; im < 4; ++im)
#pragma unroll
            for (int j = 0; j < 4; ++j) {
                int r = wr * 64 + im * 16 + hi * 4 + j;
                if (r < mv) {
                    int tok = s_tok[r];
                    float wgt = s_w[r];
                    size_t rowoff = (size_t)tok * HD;
#pragma unroll
                    for (int in = 0; in < 4; ++in) {
                        int c = ct * 128 + wc * 64 + in * 16 + rr;
                        float2 sq = __half22float2(sgp_reg[im][in][j >> 1]);
                        float sg = (j & 1) ? sq.y : sq.x;
                        float tr = accT[im][in][j];
                        float xv = x[rowoff + c];
                        float yv = sg * tr + (1.f - sg) * xv;
                        atomicAdd(&out[rowoff + c], wgt * yv);
                    }
                }
            }
    }
}

extern "C" void kernel_launch(void* const* d_in, const int* in_sizes, int n_in,
                              void* d_out, int out_size, void* d_ws, size_t ws_size,
                              hipStream_t stream)
{
    const float* x   = (const float*)d_in[0];
    const float* Wd  = (const float*)d_in[1];
    const float* bd  = (const float*)d_in[2];
    const float* cen = (const float*)d_in[3];
    const float* Wg  = (const float*)d_in[4];
    const float* bg  = (const float*)d_in[5];
    const float* U   = (const float*)d_in[6];
    const float* V   = (const float*)d_in[7];
    float* out = (float*)d_out;

    char* ws = (char*)d_ws;
    size_t off = 0;
    auto alloc = [&](size_t bytes) { size_t o = off; off = (off + bytes + 255) & ~(size_t)255; return o; };
    float* dT        = (float*)(ws + alloc((size_t)NTOK * CD * 4));
    float* cn        = (float*)(ws + alloc((size_t)NE * CD * 4));
    float* sncn      = (float*)(ws + alloc(NE * 4));
    int*   top_i     = (int*)(ws + alloc((size_t)NTOK * 2 * 4));
    float* top_w     = (float*)(ws + alloc((size_t)NTOK * 2 * 4));
    int*   counts    = (int*)(ws + alloc(NE * 4));
    int*   offsets   = (int*)(ws + alloc((NE + 1) * 4));
    int*   blkstart  = (int*)(ws + alloc((NE + 1) * 4));
    int*   cursor    = (int*)(ws + alloc(NE * 4));
    int*   list_tok  = (int*)(ws + alloc((size_t)NTOK * 2 * 4));
    float* list_w    = (float*)(ws + alloc((size_t)NTOK * 2 * 4));
    u16*   xbf       = (u16*)(ws + alloc((size_t)NTOK * HD * 2));
    u16*   xlo       = (u16*)(ws + alloc((size_t)NTOK * HD * 2));
    u16*   wdh       = (u16*)(ws + alloc((size_t)CD * HD * 2));
    u16*   wdl       = (u16*)(ws + alloc((size_t)CD * HD * 2));
    u16*   wgT       = (u16*)(ws + alloc((size_t)NE * HD * HD * 2));
    u16*   uT        = (u16*)(ws + alloc((size_t)NE * RD * HD * 2));
    u16*   vT        = (u16*)(ws + alloc((size_t)NE * RD * HD * 2));
    u16*   tbf       = (u16*)(ws + alloc(((size_t)NTOK * 2 + 128) * RD * 2));

    hipMemsetAsync(out, 0, (size_t)out_size * 4, stream);
    hipMemsetAsync(counts, 0, NE * 4, stream);

    centroid_norm_kernel<<<NE, 64, 0, stream>>>(cen, cn, sncn);
    cvt_split_kernel<<<(NTOK * HD / 4 + 255) / 256, 256, 0, stream>>>(x, xbf, xlo, NTOK * HD / 4);
    transpose_cvt_split_kernel<<<dim3(CD / 32, HD / 32), 256, 0, stream>>>(Wd, wdh, wdl, HD, CD);
    router_mfma_kernel<<<(NTOK / 128) * 2, 256, 0, stream>>>(xbf, xlo, wdh, wdl, bd, dT);
    router_score_kernel<<<NTOK / 64, 256, 0, stream>>>(dT, cn, sncn, top_i, top_w, counts);
    scan_kernel<<<1, 64, 0, stream>>>(counts, offsets, blkstart, cursor);
    build_lists_kernel<<<NTOK / 256, 256, 0, stream>>>(top_i, top_w, offsets, cursor, list_tok, list_w);

    transpose_cvt_kernel<<<dim3(HD / 32, HD / 32, NE), 256, 0, stream>>>(Wg, wgT, HD, HD);
    transpose_cvt_kernel<<<dim3(RD / 32, HD / 32, NE), 256, 0, stream>>>(U, uT, HD, RD);
    transpose_cvt_kernel<<<dim3(HD / 32, RD / 32, NE), 256, 0, stream>>>(V, vT, RD, HD);

    tproj_kernel<<<MB2, 256, 0, stream>>>(xbf, uT, list_tok, offsets, blkstart, tbf);
    expert_kernel<<<EGRID, 256, 0, stream>>>(xbf, wgT, vT, tbf, x, bg,
                                             list_tok, list_w, offsets, blkstart, out);
}

// Round 12
// 502.476 us; speedup vs baseline: 1.1120x; 1.1120x over previous
//
#include <hip/hip_runtime.h>
#include <hip/hip_bf16.h>
#include <hip/hip_fp16.h>
#include <cstdint>
#include <cstddef>

#define NTOK 16384
#define HD   1024
#define CD   256
#define NE   16
#define RD   128
#define MB2    272          // upper bound on 128-token blocks over all experts
#define LOGB   2176         // MB2 * 8 ct-tiles
#define EGRID  2304         // ceil(LOGB/256)*256  (multiple of 256 -> bijective remap)

typedef __attribute__((ext_vector_type(8))) short bf16x8;
typedef __attribute__((ext_vector_type(4))) float f32x4;
typedef unsigned short u16;
typedef unsigned int u32;

__device__ __forceinline__ u16 f2bf(float f) {
    u32 u = __float_as_uint(f);
    u32 r = (u + 0x7FFFu + ((u >> 16) & 1u)) >> 16;   // RNE
    return (u16)r;
}
__device__ __forceinline__ float bf2f(u16 h) {
    u32 u = ((u32)h) << 16;
    return __uint_as_float(u);
}

__device__ __forceinline__ void gload16(const void* g, void* lds) {
    __builtin_amdgcn_global_load_lds((const __attribute__((address_space(1))) void*)g,
                                     (__attribute__((address_space(3))) void*)lds,
                                     16, 0, 0);
}

__device__ __forceinline__ float wredsum(float v) {
#pragma unroll
    for (int m = 32; m >= 1; m >>= 1) v += __shfl_xor(v, m, 64);
    return v;
}

// ---------------- K1: normalize centroids (+ zero counts, folded) ----------------
__global__ __launch_bounds__(64) void centroid_norm_kernel(
    const float* __restrict__ cen, float* __restrict__ cn, float* __restrict__ sncn,
    int* __restrict__ counts)
{
    int e = blockIdx.x, l = threadIdx.x;
    float4 c = *(const float4*)&cen[e * CD + l * 4];
    float ss = wredsum(c.x * c.x + c.y * c.y + c.z * c.z + c.w * c.w);
    float den = fmaxf(sqrtf(ss), 1e-8f);
    float4 n;
    n.x = c.x / den; n.y = c.y / den; n.z = c.z / den; n.w = c.w / den;
    *(float4*)&cn[e * CD + l * 4] = n;
    float s2 = wredsum(n.x * n.x + n.y * n.y + n.z * n.z + n.w * n.w);
    if (l == 0) { sncn[e] = s2; counts[e] = 0; }
}

// ---------------- K2: x -> bf16 hi (xbf) + bf16 lo (xlo) ----------------
__global__ __launch_bounds__(256) void cvt_split_kernel(
    const float* __restrict__ src, u16* __restrict__ hi, u16* __restrict__ lo, int n4)
{
    int i = blockIdx.x * 256 + threadIdx.x;
    if (i >= n4) return;
    float4 v = *(const float4*)&src[(size_t)i * 4];
    ushort4 h, l;
    h.x = f2bf(v.x); h.y = f2bf(v.y); h.z = f2bf(v.z); h.w = f2bf(v.w);
    l.x = f2bf(v.x - bf2f(h.x)); l.y = f2bf(v.y - bf2f(h.y));
    l.z = f2bf(v.z - bf2f(h.z)); l.w = f2bf(v.w - bf2f(h.w));
    *(ushort4*)&hi[(size_t)i * 4] = h;
    *(ushort4*)&lo[(size_t)i * 4] = l;
}

// ---------------- K3: per-expert transpose + convert: src [K][N] -> dst [N][K] ----------------
__global__ __launch_bounds__(256) void transpose_cvt_kernel(
    const float* __restrict__ src, u16* __restrict__ dst, int K, int N)
{
    __shared__ float t[32][33];
    const float* s = src + (size_t)blockIdx.z * K * N;
    u16* d = dst + (size_t)blockIdx.z * K * N;
    int kb = blockIdx.y * 32, nb = blockIdx.x * 32;
    int r = threadIdx.x >> 3, c4 = (threadIdx.x & 7) * 4;
    float4 v = *(const float4*)&s[(size_t)(kb + r) * N + nb + c4];
    t[r][c4 + 0] = v.x; t[r][c4 + 1] = v.y; t[r][c4 + 2] = v.z; t[r][c4 + 3] = v.w;
    __syncthreads();
    ushort4 o;
    o.x = f2bf(t[c4 + 0][r]); o.y = f2bf(t[c4 + 1][r]);
    o.z = f2bf(t[c4 + 2][r]); o.w = f2bf(t[c4 + 3][r]);
    *(ushort4*)&d[(size_t)(nb + r) * K + kb + c4] = o;
}

// ---------------- K3b: Wd [K][N] -> wdh/wdl [N][K] (hi/lo split) ----------------
__global__ __launch_bounds__(256) void transpose_cvt_split_kernel(
    const float* __restrict__ src, u16* __restrict__ dh, u16* __restrict__ dl,
    int K, int N)
{
    __shared__ float t[32][33];
    int kb = blockIdx.y * 32, nb = blockIdx.x * 32;
    int r = threadIdx.x >> 3, c4 = (threadIdx.x & 7) * 4;
    float4 v = *(const float4*)&src[(size_t)(kb + r) * N + nb + c4];
    t[r][c4 + 0] = v.x; t[r][c4 + 1] = v.y; t[r][c4 + 2] = v.z; t[r][c4 + 3] = v.w;
    __syncthreads();
    float f0 = t[c4 + 0][r], f1 = t[c4 + 1][r], f2 = t[c4 + 2][r], f3 = t[c4 + 3][r];
    ushort4 h, l;
    h.x = f2bf(f0); h.y = f2bf(f1); h.z = f2bf(f2); h.w = f2bf(f3);
    l.x = f2bf(f0 - bf2f(h.x)); l.y = f2bf(f1 - bf2f(h.y));
    l.z = f2bf(f2 - bf2f(h.z)); l.w = f2bf(f3 - bf2f(h.w));
    *(ushort4*)&dh[(size_t)(nb + r) * K + kb + c4] = h;
    *(ushort4*)&dl[(size_t)(nb + r) * K + kb + c4] = l;
}

// Swizzle (all MFMA kernels): stored[row][s]=logical[row][s^((row>>1)&3)];
// stage slot sl=(lane&3)^((lane>>3)&3); read slot rslot=hi^((rr>>1)&3).
// Pipeline (verified, spill-robust): STAGE(next) -> COMP(cur) -> __syncthreads().

// ---------------- K4: router GEMM, split-bf16 MFMA ----------------
__global__ __launch_bounds__(256, 2) void router_mfma_kernel(
    const u16* __restrict__ xh, const u16* __restrict__ xl,
    const u16* __restrict__ wdh, const u16* __restrict__ wdl,
    const float* __restrict__ bd, float* __restrict__ dT)
{
    __shared__ __align__(16) u16 lds[2 * 16384];
    int rb = (blockIdx.x >> 1) * 128;
    int cb = (blockIdx.x & 1) * 128;
    int tid = threadIdx.x, lane = tid & 63, w = tid >> 6;
    int lrow = lane >> 2;
    int sl = (lane & 3) ^ ((lane >> 3) & 3);
    int rr = lane & 15, hi = lane >> 4;
    int rslot = hi ^ ((rr >> 1) & 3);
    int wr = w >> 1, wc = w & 1;

    const u16* gb[8]; char* lp[8];
#pragma unroll
    for (int i = 0; i < 8; ++i) {
        int idx = w + 4 * i;
        int sub = idx & 7;
        int row = sub * 16 + lrow;
        if (idx < 8) {
            gb[i] = xh + (size_t)(rb + row) * HD + sl * 8;
            lp[i] = (char*)lds + idx * 1024;
        } else if (idx < 16) {
            gb[i] = xl + (size_t)(rb + row) * HD + sl * 8;
            lp[i] = (char*)lds + 8192 + sub * 1024;
        } else if (idx < 24) {
            gb[i] = wdh + (size_t)(cb + row) * HD + sl * 8;
            lp[i] = (char*)lds + 16384 + sub * 1024;
        } else {
            gb[i] = wdl + (size_t)(cb + row) * HD + sl * 8;
            lp[i] = (char*)lds + 24576 + sub * 1024;
        }
    }

    const f32x4 zz = {0.f, 0.f, 0.f, 0.f};
    f32x4 acc[4][4];
#pragma unroll
    for (int im = 0; im < 4; ++im)
#pragma unroll
        for (int in = 0; in < 4; ++in) acc[im][in] = zz;

    auto STAGE = [&](int buf, int t) {
#pragma unroll
        for (int i = 0; i < 8; ++i) gload16(gb[i] + t * 32, lp[i] + buf * 32768);
    };
    auto COMP = [&](int buf) {
        const u16* LXH = lds + buf * 16384;
        const u16* LXL = LXH + 4096;
        const u16* LWH = LXH + 8192;
        const u16* LWL = LXH + 12288;
        bf16x8 ah[4], al[4], bh[4], bl[4];
#pragma unroll
        for (int im = 0; im < 4; ++im) {
            int row = wr * 64 + im * 16 + rr;
            ah[im] = *(const bf16x8*)&LXH[row * 32 + rslot * 8];
            al[im] = *(const bf16x8*)&LXL[row * 32 + rslot * 8];
        }
#pragma unroll
        for (int in = 0; in < 4; ++in) {
            int row = wc * 64 + in * 16 + rr;
            bh[in] = *(const bf16x8*)&LWH[row * 32 + rslot * 8];
            bl[in] = *(const bf16x8*)&LWL[row * 32 + rslot * 8];
        }
#pragma unroll
        for (int im = 0; im < 4; ++im)
#pragma unroll
            for (int in = 0; in < 4; ++in) {
                acc[im][in] = __builtin_amdgcn_mfma_f32_16x16x32_bf16(ah[im], bh[in], acc[im][in], 0, 0, 0);
                acc[im][in] = __builtin_amdgcn_mfma_f32_16x16x32_bf16(ah[im], bl[in], acc[im][in], 0, 0, 0);
                acc[im][in] = __builtin_amdgcn_mfma_f32_16x16x32_bf16(al[im], bh[in], acc[im][in], 0, 0, 0);
            }
    };

    STAGE(0, 0);
    __syncthreads();
    for (int t = 0; t < 31; ++t) {
        STAGE((t + 1) & 1, t + 1);
        COMP(t & 1);
        __syncthreads();
    }
    COMP(1);

#pragma unroll
    for (int im = 0; im < 4; ++im)
#pragma unroll
        for (int in = 0; in < 4; ++in) {
            int c = cb + wc * 64 + in * 16 + rr;
            float b = bd[c];
            float g[4];
#pragma unroll
            for (int j = 0; j < 4; ++j) {
                float v = acc[im][in][j] + b;
                g[j] = 0.5f * v * (1.f + erff(v * 0.70710678118654752f));
            }
            float4 o = {g[0], g[1], g[2], g[3]};
            *(float4*)&dT[(size_t)c * NTOK + rb + wr * 64 + im * 16 + hi * 4] = o;
        }
}

// ---------------- K5: router score — lane-local dots, no shuffles ----------------
__global__ __launch_bounds__(256) void router_score_kernel(
    const float* __restrict__ dT, const float* __restrict__ cn,
    const float* __restrict__ sncn, int* __restrict__ top_i,
    float* __restrict__ top_w, int* __restrict__ counts)
{
    __shared__ float lcn[NE][CD];
    __shared__ float sdot[NE][64];
    __shared__ float sss[64];
    __shared__ int hist[NE];
    int tid = threadIdx.x, lane = tid & 63, w = tid >> 6;
    for (int i = tid; i < NE * CD / 4; i += 256)
        ((float4*)&lcn[0][0])[i] = ((const float4*)cn)[i];
    if (tid < NE) hist[tid] = 0;
    __syncthreads();

    int tokbase = blockIdx.x * 64;
    const float* p = dT + tokbase + lane;
    int e0 = w * 4;
    float d0 = 0.f, d1 = 0.f, d2a = 0.f, d3 = 0.f, ss = 0.f;
#pragma unroll 4
    for (int k = 0; k < CD; ++k) {
        float v = p[(size_t)k * NTOK];
        ss = fmaf(v, v, ss);
        d0 = fmaf(v, lcn[e0 + 0][k], d0);
        d1 = fmaf(v, lcn[e0 + 1][k], d1);
        d2a = fmaf(v, lcn[e0 + 2][k], d2a);
        d3 = fmaf(v, lcn[e0 + 3][k], d3);
    }
    sdot[e0 + 0][lane] = d0;
    sdot[e0 + 1][lane] = d1;
    sdot[e0 + 2][lane] = d2a;
    sdot[e0 + 3][lane] = d3;
    if (w == 0) sss[lane] = ss;
    __syncthreads();

    if (tid < 64) {
        int tok = tokbase + tid;
        float ssv = sss[tid];
        float den = fmaxf(sqrtf(ssv), 1e-8f);
        float inv = 1.f / den;
        float sndn = (ssv * inv) * inv;
        float pr[NE];
#pragma unroll
        for (int e = 0; e < NE; ++e) {
            float dotn = sdot[e][tid] * inv;
            float dd2 = sndn + sncn[e] - 2.f * dotn;
            pr[e] = -sqrtf(fmaxf(dd2, 0.f));
        }
        float mx = pr[0];
#pragma unroll
        for (int e = 1; e < NE; ++e) mx = fmaxf(mx, pr[e]);
        float sum = 0.f;
#pragma unroll
        for (int e = 0; e < NE; ++e) { pr[e] = expf(pr[e] - mx); sum += pr[e]; }
        float invs = 1.f / sum;
#pragma unroll
        for (int e = 0; e < NE; ++e) pr[e] *= invs;
        int i1 = 0; float p1 = pr[0];
#pragma unroll
        for (int e = 1; e < NE; ++e) if (pr[e] > p1) { p1 = pr[e]; i1 = e; }
        int i2 = -1; float p2 = -1.f;
#pragma unroll
        for (int e = 0; e < NE; ++e) if (e != i1 && pr[e] > p2) { p2 = pr[e]; i2 = e; }
        top_i[tok * 2 + 0] = i1; top_w[tok * 2 + 0] = p1;
        top_i[tok * 2 + 1] = i2; top_w[tok * 2 + 1] = p2;
        atomicAdd(&hist[i1], 1);
        atomicAdd(&hist[i2], 1);
    }
    __syncthreads();
    if (tid < NE) atomicAdd(&counts[tid], hist[tid]);
}

// ---------------- K6: tiny scan (128-row blocks) ----------------
__global__ void scan_kernel(const int* __restrict__ counts, int* __restrict__ offsets,
                            int* __restrict__ blkstart, int* __restrict__ cursor)
{
    if (threadIdx.x == 0 && blockIdx.x == 0) {
        int o = 0, b = 0;
        for (int e = 0; e < NE; ++e) {
            offsets[e] = o; blkstart[e] = b; cursor[e] = 0;
            o += counts[e]; b += (counts[e] + 127) >> 7;
        }
        offsets[NE] = o; blkstart[NE] = b;
    }
}

// ---------------- K7: build per-expert token lists ----------------
__global__ __launch_bounds__(256) void build_lists_kernel(
    const int* __restrict__ top_i, const float* __restrict__ top_w,
    const int* __restrict__ offsets, int* __restrict__ cursor,
    int* __restrict__ list_tok, float* __restrict__ list_w)
{
    int t = blockIdx.x * 256 + threadIdx.x;
#pragma unroll
    for (int j = 0; j < 2; ++j) {
        int e = top_i[t * 2 + j];
        int pos = atomicAdd(&cursor[e], 1);
        int idx = offsets[e] + pos;
        list_tok[idx] = t;
        list_w[idx] = top_w[t * 2 + j];
    }
}

// ---------------- K8: t = x @ U_e — M=128 ----------------
// Live set ~50 VGPR + 64 AGPR = ~114 < 128 cap -> (256,4) spill-free, 4 blocks/CU.
__global__ __launch_bounds__(256, 4) void tproj_kernel(
    const u16* __restrict__ xbf, const u16* __restrict__ uT,
    const int* __restrict__ list_tok, const int* __restrict__ offsets,
    const int* __restrict__ blkstart, u16* __restrict__ tbf)
{
    __shared__ __align__(16) u16 lds[2 * 8192];
    __shared__ int s_tok[128];
    int mb = blockIdx.x;
    int e = 0;
#pragma unroll
    for (int i = 0; i < NE; ++i) if (mb >= blkstart[i + 1]) e = i + 1;
    if (e >= NE) return;
    int mloc = (mb - blkstart[e]) * 128;
    int base = offsets[e] + mloc;
    int cnt = offsets[e + 1] - offsets[e];
    int mv = min(128, cnt - mloc);
    int tid = threadIdx.x, lane = tid & 63, w = tid >> 6;
    if (tid < 128) s_tok[tid] = list_tok[base + (tid < mv ? tid : 0)];
    __syncthreads();
    int lrow = lane >> 2;
    int sl = (lane & 3) ^ ((lane >> 3) & 3);
    int rr = lane & 15, hi = lane >> 4;
    int rslot = hi ^ ((rr >> 1) & 3);
    int wr = w >> 1, wc = w & 1;
    const u16* uE = uT + (size_t)e * RD * HD;

    const u16* gb[4]; char* lp[4];
#pragma unroll
    for (int i = 0; i < 4; ++i) {
        int idx = w + 4 * i;
        if (idx < 8) {
            int row = idx * 16 + lrow;
            gb[i] = xbf + (size_t)s_tok[row] * HD + sl * 8;
            lp[i] = (char*)lds + idx * 1024;
        } else {
            int row = (idx - 8) * 16 + lrow;
            gb[i] = uE + (size_t)row * HD + sl * 8;
            lp[i] = (char*)lds + 8192 + (idx - 8) * 1024;
        }
    }
    const f32x4 zz = {0.f, 0.f, 0.f, 0.f};
    f32x4 acc[4][4];
#pragma unroll
    for (int im = 0; im < 4; ++im)
#pragma unroll
        for (int in = 0; in < 4; ++in) acc[im][in] = zz;

    auto STAGE = [&](int buf, int t) {
#pragma unroll
        for (int i = 0; i < 4; ++i) gload16(gb[i] + t * 32, lp[i] + buf * 16384);
    };
    auto COMP = [&](int buf, f32x4 (&a)[4][4]) {
        const u16* LA = lds + buf * 8192;
        const u16* LB = LA + 4096;
        bf16x8 af[4], bfv[4];
#pragma unroll
        for (int im = 0; im < 4; ++im) af[im] = *(const bf16x8*)&LA[(wr * 64 + im * 16 + rr) * 32 + rslot * 8];
#pragma unroll
        for (int in = 0; in < 4; ++in) bfv[in] = *(const bf16x8*)&LB[(wc * 64 + in * 16 + rr) * 32 + rslot * 8];
#pragma unroll
        for (int im = 0; im < 4; ++im)
#pragma unroll
            for (int in = 0; in < 4; ++in)
                a[im][in] = __builtin_amdgcn_mfma_f32_16x16x32_bf16(af[im], bfv[in], a[im][in], 0, 0, 0);
    };

    STAGE(0, 0);
    __syncthreads();
    for (int t = 0; t < 31; ++t) {
        STAGE((t + 1) & 1, t + 1);
        COMP(t & 1, acc);
        __syncthreads();
    }
    COMP(1, acc);

#pragma unroll
    for (int im = 0; im < 4; ++im)
#pragma unroll
        for (int in = 0; in < 4; ++in)
#pragma unroll
            for (int j = 0; j < 4; ++j) {
                int r = wr * 64 + im * 16 + hi * 4 + j;
                if (r < mv) {
                    int c = wc * 64 + in * 16 + rr;
                    tbf[(size_t)(base + r) * RD + c] = f2bf(acc[im][in][j]);
                }
            }
}

// ---------------- K9: trans GEMM + gate GEMM + highway epilogue (R10 verbatim) ----------------
// XCD remap gives each XCD a run of 32 consecutive l. 2D run tiling: run = 8 mb x 4 ct
//   g=l>>5, i=l&31: mb=(g>>1)*8+(i&7), ct=(g&1)*4+(i>>3)
__global__ __launch_bounds__(256, 3) void expert_kernel(
    const u16* __restrict__ xbf, const u16* __restrict__ wgT,
    const u16* __restrict__ vT, const u16* __restrict__ tbf,
    const float* __restrict__ x, const float* __restrict__ bg,
    const int* __restrict__ list_tok, const float* __restrict__ list_w,
    const int* __restrict__ offsets, const int* __restrict__ blkstart,
    float* __restrict__ out)
{
    __shared__ __align__(16) u16 lds[2 * 8192];
    __shared__ int s_tok[128];
    __shared__ float s_w[128];
    int d = blockIdx.x;
    int l = (d >> 8) * 256 + (d & 7) * 32 + ((d & 255) >> 3);
    if (l >= LOGB) return;
    int g = l >> 5, i2d = l & 31;
    int mb = (g >> 1) * 8 + (i2d & 7);
    int ct = (g & 1) * 4 + (i2d >> 3);
    int e = 0;
#pragma unroll
    for (int i = 0; i < NE; ++i) if (mb >= blkstart[i + 1]) e = i + 1;
    if (e >= NE) return;
    int mloc = (mb - blkstart[e]) * 128;
    int base = offsets[e] + mloc;
    int cnt = offsets[e + 1] - offsets[e];
    int mv = min(128, cnt - mloc);
    int tid = threadIdx.x, lane = tid & 63, w = tid >> 6;
    if (tid < 128) {
        int p = base + (tid < mv ? tid : 0);
        s_tok[tid] = list_tok[p];
        s_w[tid] = (tid < mv) ? list_w[p] : 0.f;
    }
    __syncthreads();
    int lrow = lane >> 2;
    int sl = (lane & 3) ^ ((lane >> 3) & 3);
    int rr = lane & 15, hi = lane >> 4;
    int rslot = hi ^ ((rr >> 1) & 3);
    int wr = w >> 1, wc = w & 1;

    const u16* wgE = wgT + (size_t)e * HD * HD + (size_t)(ct * 128) * HD;
    const u16* vE  = vT  + (size_t)e * HD * RD + (size_t)(ct * 128) * RD;

    char* lp[4];
    const u16* gbT[4]; const u16* gbG[4];
#pragma unroll
    for (int i = 0; i < 4; ++i) {
        int idx = w + 4 * i;
        if (idx < 8) {
            int row = idx * 16 + lrow;
            lp[i]  = (char*)lds + idx * 1024;
            gbT[i] = tbf + (size_t)(base + (row < mv ? row : 0)) * RD + sl * 8;
            gbG[i] = xbf + (size_t)s_tok[row] * HD + sl * 8;
        } else {
            int row = (idx - 8) * 16 + lrow;
            lp[i]  = (char*)lds + 8192 + (idx - 8) * 1024;
            gbT[i] = vE  + (size_t)row * RD + sl * 8;
            gbG[i] = wgE + (size_t)row * HD + sl * 8;
        }
    }

    auto STAGE = [&](int buf, int t, const u16* const (&gb)[4]) {
#pragma unroll
        for (int i = 0; i < 4; ++i) gload16(gb[i] + t * 32, lp[i] + buf * 16384);
    };
    auto COMP = [&](int buf, f32x4 (&a)[4][4]) {
        const u16* LA = lds + buf * 8192;
        const u16* LB = LA + 4096;
        bf16x8 af[4], bfv[4];
#pragma unroll
        for (int im = 0; im < 4; ++im) af[im] = *(const bf16x8*)&LA[(wr * 64 + im * 16 + rr) * 32 + rslot * 8];
#pragma unroll
        for (int in = 0; in < 4; ++in) bfv[in] = *(const bf16x8*)&LB[(wc * 64 + in * 16 + rr) * 32 + rslot * 8];
#pragma unroll
        for (int im = 0; im < 4; ++im)
#pragma unroll
            for (int in = 0; in < 4; ++in)
                a[im][in] = __builtin_amdgcn_mfma_f32_16x16x32_bf16(af[im], bfv[in], a[im][in], 0, 0, 0);
    };

    const f32x4 zz = {0.f, 0.f, 0.f, 0.f};
    f32x4 accT[4][4];
#pragma unroll
    for (int im = 0; im < 4; ++im)
#pragma unroll
        for (int in = 0; in < 4; ++in) accT[im][in] = zz;

    STAGE(0, 0, gbT);
    __syncthreads();
#pragma unroll
    for (int s = 0; s < 4; ++s) {
        if (s < 3) STAGE((s + 1) & 1, s + 1, gbT);
        else       STAGE(0, 0, gbG);
        COMP(s & 1, accT);
        __syncthreads();
    }

    __half2 tpk[4][4][2];
#pragma unroll
    for (int im = 0; im < 4; ++im)
#pragma unroll
        for (int in = 0; in < 4; ++in) {
            tpk[im][in][0] = __floats2half2_rn(accT[im][in][0], accT[im][in][1]);
            tpk[im][in][1] = __floats2half2_rn(accT[im][in][2], accT[im][in][3]);
        }

    f32x4 accG[4][4];
#pragma unroll
    for (int im = 0; im < 4; ++im)
#pragma unroll
        for (int in = 0; in < 4; ++in) accG[im][in] = zz;

    for (int t = 0; t < 31; ++t) {
        STAGE((t + 1) & 1, t + 1, gbG);
        COMP(t & 1, accG);
        __syncthreads();
    }
    COMP(1, accG);

    float bgv[4];
#pragma unroll
    for (int in = 0; in < 4; ++in)
        bgv[in] = bg[e * HD + ct * 128 + wc * 64 + in * 16 + rr];

#pragma unroll
    for (int im = 0; im < 4; ++im)
#pragma unroll
        for (int j = 0; j < 4; ++j) {
            int r = wr * 64 + im * 16 + hi * 4 + j;
            if (r < mv) {
                int tok = s_tok[r];
                float wgt = s_w[r];
                size_t rowoff = (size_t)tok * HD;
#pragma unroll
                for (int in = 0; in < 4; ++in) {
                    int c = ct * 128 + wc * 64 + in * 16 + rr;
                    float gp = accG[im][in][j] + bgv[in];
                    float sg = 1.f / (1.f + __expf(-gp));
                    float2 tq = __half22float2(tpk[im][in][j >> 1]);
                    float tr = (j & 1) ? tq.y : tq.x;
                    float xv = x[rowoff + c];
                    float yv = sg * tr + (1.f - sg) * xv;
                    atomicAdd(&out[rowoff + c], wgt * yv);
                }
            }
        }
}

extern "C" void kernel_launch(void* const* d_in, const int* in_sizes, int n_in,
                              void* d_out, int out_size, void* d_ws, size_t ws_size,
                              hipStream_t stream)
{
    const float* x   = (const float*)d_in[0];
    const float* Wd  = (const float*)d_in[1];
    const float* bd  = (const float*)d_in[2];
    const float* cen = (const float*)d_in[3];
    const float* Wg  = (const float*)d_in[4];
    const float* bg  = (const float*)d_in[5];
    const float* U   = (const float*)d_in[6];
    const float* V   = (const float*)d_in[7];
    float* out = (float*)d_out;

    char* ws = (char*)d_ws;
    size_t off = 0;
    auto alloc = [&](size_t bytes) { size_t o = off; off = (off + bytes + 255) & ~(size_t)255; return o; };
    float* dT        = (float*)(ws + alloc((size_t)NTOK * CD * 4));
    float* cn        = (float*)(ws + alloc((size_t)NE * CD * 4));
    float* sncn      = (float*)(ws + alloc(NE * 4));
    int*   top_i     = (int*)(ws + alloc((size_t)NTOK * 2 * 4));
    float* top_w     = (float*)(ws + alloc((size_t)NTOK * 2 * 4));
    int*   counts    = (int*)(ws + alloc(NE * 4));
    int*   offsets   = (int*)(ws + alloc((NE + 1) * 4));
    int*   blkstart  = (int*)(ws + alloc((NE + 1) * 4));
    int*   cursor    = (int*)(ws + alloc(NE * 4));
    int*   list_tok  = (int*)(ws + alloc((size_t)NTOK * 2 * 4));
    float* list_w    = (float*)(ws + alloc((size_t)NTOK * 2 * 4));
    u16*   xbf       = (u16*)(ws + alloc((size_t)NTOK * HD * 2));
    u16*   xlo       = (u16*)(ws + alloc((size_t)NTOK * HD * 2));
    u16*   wdh       = (u16*)(ws + alloc((size_t)CD * HD * 2));
    u16*   wdl       = (u16*)(ws + alloc((size_t)CD * HD * 2));
    u16*   wgT       = (u16*)(ws + alloc((size_t)NE * HD * HD * 2));
    u16*   uT        = (u16*)(ws + alloc((size_t)NE * RD * HD * 2));
    u16*   vT        = (u16*)(ws + alloc((size_t)NE * RD * HD * 2));
    u16*   tbf       = (u16*)(ws + alloc(((size_t)NTOK * 2 + 128) * RD * 2));

    hipMemsetAsync(out, 0, (size_t)out_size * 4, stream);

    centroid_norm_kernel<<<NE, 64, 0, stream>>>(cen, cn, sncn, counts);
    cvt_split_kernel<<<(NTOK * HD / 4 + 255) / 256, 256, 0, stream>>>(x, xbf, xlo, NTOK * HD / 4);
    transpose_cvt_split_kernel<<<dim3(CD / 32, HD / 32), 256, 0, stream>>>(Wd, wdh, wdl, HD, CD);
    router_mfma_kernel<<<(NTOK / 128) * 2, 256, 0, stream>>>(xbf, xlo, wdh, wdl, bd, dT);
    router_score_kernel<<<NTOK / 64, 256, 0, stream>>>(dT, cn, sncn, top_i, top_w, counts);
    scan_kernel<<<1, 64, 0, stream>>>(counts, offsets, blkstart, cursor);
    build_lists_kernel<<<NTOK / 256, 256, 0, stream>>>(top_i, top_w, offsets, cursor, list_tok, list_w);

    transpose_cvt_kernel<<<dim3(HD / 32, HD / 32, NE), 256, 0, stream>>>(Wg, wgT, HD, HD);
    transpose_cvt_kernel<<<dim3(RD / 32, HD / 32, NE), 256, 0, stream>>>(U, uT, HD, RD);
    transpose_cvt_kernel<<<dim3(HD / 32, RD / 32, NE), 256, 0, stream>>>(V, vT, RD, HD);

    tproj_kernel<<<MB2, 256, 0, stream>>>(xbf, uT, list_tok, offsets, blkstart, tbf);
    expert_kernel<<<EGRID, 256, 0, stream>>>(xbf, wgT, vT, tbf, x, bg,
                                             list_tok, list_w, offsets, blkstart, out);
}

// Round 13
// 489.097 us; speedup vs baseline: 1.1424x; 1.0274x over previous
//
#include <hip/hip_runtime.h>
#include <hip/hip_bf16.h>
#include <hip/hip_fp16.h>
#include <cstdint>
#include <cstddef>

#define NTOK 16384
#define HD   1024
#define CD   256
#define NE   16
#define RD   128
#define MB64   528          // upper bound on 64-token blocks (tproj)
#define LOGB   2176         // 128-token blocks * 8 ct-tiles (expert)
#define EGRID  2304         // ceil(LOGB/256)*256  (multiple of 256 -> bijective remap)

typedef __attribute__((ext_vector_type(8))) short bf16x8;
typedef __attribute__((ext_vector_type(4))) float f32x4;
typedef unsigned short u16;
typedef unsigned int u32;

__device__ __forceinline__ u16 f2bf(float f) {
    u32 u = __float_as_uint(f);
    u32 r = (u + 0x7FFFu + ((u >> 16) & 1u)) >> 16;   // RNE
    return (u16)r;
}
__device__ __forceinline__ float bf2f(u16 h) {
    u32 u = ((u32)h) << 16;
    return __uint_as_float(u);
}

__device__ __forceinline__ void gload16(const void* g, void* lds) {
    __builtin_amdgcn_global_load_lds((const __attribute__((address_space(1))) void*)g,
                                     (__attribute__((address_space(3))) void*)lds,
                                     16, 0, 0);
}

__device__ __forceinline__ float wredsum(float v) {
#pragma unroll
    for (int m = 32; m >= 1; m >>= 1) v += __shfl_xor(v, m, 64);
    return v;
}

// ---------------- K1: normalize centroids (+ zero counts, folded) ----------------
__global__ __launch_bounds__(64) void centroid_norm_kernel(
    const float* __restrict__ cen, float* __restrict__ cn, float* __restrict__ sncn,
    int* __restrict__ counts)
{
    int e = blockIdx.x, l = threadIdx.x;
    float4 c = *(const float4*)&cen[e * CD + l * 4];
    float ss = wredsum(c.x * c.x + c.y * c.y + c.z * c.z + c.w * c.w);
    float den = fmaxf(sqrtf(ss), 1e-8f);
    float4 n;
    n.x = c.x / den; n.y = c.y / den; n.z = c.z / den; n.w = c.w / den;
    *(float4*)&cn[e * CD + l * 4] = n;
    float s2 = wredsum(n.x * n.x + n.y * n.y + n.z * n.z + n.w * n.w);
    if (l == 0) { sncn[e] = s2; counts[e] = 0; }
}

// ---------------- K2: x -> bf16 hi (xbf) + bf16 lo (xlo) ----------------
__global__ __launch_bounds__(256) void cvt_split_kernel(
    const float* __restrict__ src, u16* __restrict__ hi, u16* __restrict__ lo, int n4)
{
    int i = blockIdx.x * 256 + threadIdx.x;
    if (i >= n4) return;
    float4 v = *(const float4*)&src[(size_t)i * 4];
    ushort4 h, l;
    h.x = f2bf(v.x); h.y = f2bf(v.y); h.z = f2bf(v.z); h.w = f2bf(v.w);
    l.x = f2bf(v.x - bf2f(h.x)); l.y = f2bf(v.y - bf2f(h.y));
    l.z = f2bf(v.z - bf2f(h.z)); l.w = f2bf(v.w - bf2f(h.w));
    *(ushort4*)&hi[(size_t)i * 4] = h;
    *(ushort4*)&lo[(size_t)i * 4] = l;
}

// ---------------- K3: per-expert transpose + convert: src [K][N] -> dst [N][K] ----------------
__global__ __launch_bounds__(256) void transpose_cvt_kernel(
    const float* __restrict__ src, u16* __restrict__ dst, int K, int N)
{
    __shared__ float t[32][33];
    const float* s = src + (size_t)blockIdx.z * K * N;
    u16* d = dst + (size_t)blockIdx.z * K * N;
    int kb = blockIdx.y * 32, nb = blockIdx.x * 32;
    int r = threadIdx.x >> 3, c4 = (threadIdx.x & 7) * 4;
    float4 v = *(const float4*)&s[(size_t)(kb + r) * N + nb + c4];
    t[r][c4 + 0] = v.x; t[r][c4 + 1] = v.y; t[r][c4 + 2] = v.z; t[r][c4 + 3] = v.w;
    __syncthreads();
    ushort4 o;
    o.x = f2bf(t[c4 + 0][r]); o.y = f2bf(t[c4 + 1][r]);
    o.z = f2bf(t[c4 + 2][r]); o.w = f2bf(t[c4 + 3][r]);
    *(ushort4*)&d[(size_t)(nb + r) * K + kb + c4] = o;
}

// ---------------- K3b: Wd [K][N] -> wdh/wdl [N][K] (hi/lo split) ----------------
__global__ __launch_bounds__(256) void transpose_cvt_split_kernel(
    const float* __restrict__ src, u16* __restrict__ dh, u16* __restrict__ dl,
    int K, int N)
{
    __shared__ float t[32][33];
    int kb = blockIdx.y * 32, nb = blockIdx.x * 32;
    int r = threadIdx.x >> 3, c4 = (threadIdx.x & 7) * 4;
    float4 v = *(const float4*)&src[(size_t)(kb + r) * N + nb + c4];
    t[r][c4 + 0] = v.x; t[r][c4 + 1] = v.y; t[r][c4 + 2] = v.z; t[r][c4 + 3] = v.w;
    __syncthreads();
    float f0 = t[c4 + 0][r], f1 = t[c4 + 1][r], f2 = t[c4 + 2][r], f3 = t[c4 + 3][r];
    ushort4 h, l;
    h.x = f2bf(f0); h.y = f2bf(f1); h.z = f2bf(f2); h.w = f2bf(f3);
    l.x = f2bf(f0 - bf2f(h.x)); l.y = f2bf(f1 - bf2f(h.y));
    l.z = f2bf(f2 - bf2f(h.z)); l.w = f2bf(f3 - bf2f(h.w));
    *(ushort4*)&dh[(size_t)(nb + r) * K + kb + c4] = h;
    *(ushort4*)&dl[(size_t)(nb + r) * K + kb + c4] = l;
}

// Swizzle (all MFMA kernels): stored[row][s]=logical[row][s^((row>>1)&3)];
// stage slot sl=(lane&3)^((lane>>3)&3); read slot rslot=hi^((rr>>1)&3).
// Pipeline (verified, spill-robust): STAGE(next) -> COMP(cur) -> __syncthreads().

// ---------------- K4: router GEMM, split-bf16 MFMA — M=64 x N=128 (grid 512, 2/CU) ----------------
// distilled ~ xh@wh + xh@wl + xl@wh (rel err ~2^-17), stored dT[C][N].
// 24 staging chunks/step (A: xh 4 + xl 4, B: wdh 8 + wdl 8) = 24KB, dbuf 48KB.
__global__ __launch_bounds__(256, 3) void router_mfma_kernel(
    const u16* __restrict__ xh, const u16* __restrict__ xl,
    const u16* __restrict__ wdh, const u16* __restrict__ wdl,
    const float* __restrict__ bd, float* __restrict__ dT)
{
    __shared__ __align__(16) u16 lds[2 * 12288];
    int rb = (blockIdx.x >> 1) * 64;
    int cb = (blockIdx.x & 1) * 128;
    int tid = threadIdx.x, lane = tid & 63, w = tid >> 6;
    int lrow = lane >> 2;
    int sl = (lane & 3) ^ ((lane >> 3) & 3);
    int rr = lane & 15, hi = lane >> 4;
    int rslot = hi ^ ((rr >> 1) & 3);
    int wr = w >> 1, wc = w & 1;

    // chunks: 0..3 xh rows(64), 4..7 xl rows, 8..15 wdh rows(128), 16..23 wdl rows
    const u16* gb[6]; char* lp[6];
#pragma unroll
    for (int i = 0; i < 6; ++i) {
        int idx = w + 4 * i;
        if (idx < 4) {
            int row = idx * 16 + lrow;
            gb[i] = xh + (size_t)(rb + row) * HD + sl * 8;
            lp[i] = (char*)lds + idx * 1024;
        } else if (idx < 8) {
            int row = (idx - 4) * 16 + lrow;
            gb[i] = xl + (size_t)(rb + row) * HD + sl * 8;
            lp[i] = (char*)lds + 4096 + (idx - 4) * 1024;
        } else if (idx < 16) {
            int row = (idx - 8) * 16 + lrow;
            gb[i] = wdh + (size_t)(cb + row) * HD + sl * 8;
            lp[i] = (char*)lds + 8192 + (idx - 8) * 1024;
        } else {
            int row = (idx - 16) * 16 + lrow;
            gb[i] = wdl + (size_t)(cb + row) * HD + sl * 8;
            lp[i] = (char*)lds + 16384 + (idx - 16) * 1024;
        }
    }

    const f32x4 zz = {0.f, 0.f, 0.f, 0.f};
    f32x4 acc[2][4];
#pragma unroll
    for (int im = 0; im < 2; ++im)
#pragma unroll
        for (int in = 0; in < 4; ++in) acc[im][in] = zz;

    auto STAGE = [&](int buf, int t) {
#pragma unroll
        for (int i = 0; i < 6; ++i) gload16(gb[i] + t * 32, lp[i] + buf * 24576);
    };
    auto COMP = [&](int buf) {
        const u16* LXH = lds + buf * 12288;      // 64 rows x 32
        const u16* LXL = LXH + 2048;
        const u16* LWH = LXH + 4096;             // 128 rows x 32
        const u16* LWL = LXH + 8192;
        bf16x8 ah[2], al[2], bh[4], bl[4];
#pragma unroll
        for (int im = 0; im < 2; ++im) {
            int row = wr * 32 + im * 16 + rr;
            ah[im] = *(const bf16x8*)&LXH[row * 32 + rslot * 8];
            al[im] = *(const bf16x8*)&LXL[row * 32 + rslot * 8];
        }
#pragma unroll
        for (int in = 0; in < 4; ++in) {
            int row = wc * 64 + in * 16 + rr;
            bh[in] = *(const bf16x8*)&LWH[row * 32 + rslot * 8];
            bl[in] = *(const bf16x8*)&LWL[row * 32 + rslot * 8];
        }
#pragma unroll
        for (int im = 0; im < 2; ++im)
#pragma unroll
            for (int in = 0; in < 4; ++in) {
                acc[im][in] = __builtin_amdgcn_mfma_f32_16x16x32_bf16(ah[im], bh[in], acc[im][in], 0, 0, 0);
                acc[im][in] = __builtin_amdgcn_mfma_f32_16x16x32_bf16(ah[im], bl[in], acc[im][in], 0, 0, 0);
                acc[im][in] = __builtin_amdgcn_mfma_f32_16x16x32_bf16(al[im], bh[in], acc[im][in], 0, 0, 0);
            }
    };

    STAGE(0, 0);
    __syncthreads();
    for (int t = 0; t < 31; ++t) {
        STAGE((t + 1) & 1, t + 1);
        COMP(t & 1);
        __syncthreads();
    }
    COMP(1);

    // epilogue: gelu + transposed store dT[c][tok], float4 over the j-rows
#pragma unroll
    for (int im = 0; im < 2; ++im)
#pragma unroll
        for (int in = 0; in < 4; ++in) {
            int c = cb + wc * 64 + in * 16 + rr;
            float b = bd[c];
            float g[4];
#pragma unroll
            for (int j = 0; j < 4; ++j) {
                float v = acc[im][in][j] + b;
                g[j] = 0.5f * v * (1.f + erff(v * 0.70710678118654752f));
            }
            float4 o = {g[0], g[1], g[2], g[3]};
            *(float4*)&dT[(size_t)c * NTOK + rb + wr * 32 + im * 16 + hi * 4] = o;
        }
}

// ---------------- K5: router score — lane-local dots, no shuffles ----------------
__global__ __launch_bounds__(256) void router_score_kernel(
    const float* __restrict__ dT, const float* __restrict__ cn,
    const float* __restrict__ sncn, int* __restrict__ top_i,
    float* __restrict__ top_w, int* __restrict__ counts)
{
    __shared__ float lcn[NE][CD];
    __shared__ float sdot[NE][64];
    __shared__ float sss[64];
    __shared__ int hist[NE];
    int tid = threadIdx.x, lane = tid & 63, w = tid >> 6;
    for (int i = tid; i < NE * CD / 4; i += 256)
        ((float4*)&lcn[0][0])[i] = ((const float4*)cn)[i];
    if (tid < NE) hist[tid] = 0;
    __syncthreads();

    int tokbase = blockIdx.x * 64;
    const float* p = dT + tokbase + lane;
    int e0 = w * 4;
    float d0 = 0.f, d1 = 0.f, d2a = 0.f, d3 = 0.f, ss = 0.f;
#pragma unroll 4
    for (int k = 0; k < CD; ++k) {
        float v = p[(size_t)k * NTOK];
        ss = fmaf(v, v, ss);
        d0 = fmaf(v, lcn[e0 + 0][k], d0);
        d1 = fmaf(v, lcn[e0 + 1][k], d1);
        d2a = fmaf(v, lcn[e0 + 2][k], d2a);
        d3 = fmaf(v, lcn[e0 + 3][k], d3);
    }
    sdot[e0 + 0][lane] = d0;
    sdot[e0 + 1][lane] = d1;
    sdot[e0 + 2][lane] = d2a;
    sdot[e0 + 3][lane] = d3;
    if (w == 0) sss[lane] = ss;
    __syncthreads();

    if (tid < 64) {
        int tok = tokbase + tid;
        float ssv = sss[tid];
        float den = fmaxf(sqrtf(ssv), 1e-8f);
        float inv = 1.f / den;
        float sndn = (ssv * inv) * inv;
        float pr[NE];
#pragma unroll
        for (int e = 0; e < NE; ++e) {
            float dotn = sdot[e][tid] * inv;
            float dd2 = sndn + sncn[e] - 2.f * dotn;
            pr[e] = -sqrtf(fmaxf(dd2, 0.f));
        }
        float mx = pr[0];
#pragma unroll
        for (int e = 1; e < NE; ++e) mx = fmaxf(mx, pr[e]);
        float sum = 0.f;
#pragma unroll
        for (int e = 0; e < NE; ++e) { pr[e] = expf(pr[e] - mx); sum += pr[e]; }
        float invs = 1.f / sum;
#pragma unroll
        for (int e = 0; e < NE; ++e) pr[e] *= invs;
        int i1 = 0; float p1 = pr[0];
#pragma unroll
        for (int e = 1; e < NE; ++e) if (pr[e] > p1) { p1 = pr[e]; i1 = e; }
        int i2 = -1; float p2 = -1.f;
#pragma unroll
        for (int e = 0; e < NE; ++e) if (e != i1 && pr[e] > p2) { p2 = pr[e]; i2 = e; }
        top_i[tok * 2 + 0] = i1; top_w[tok * 2 + 0] = p1;
        top_i[tok * 2 + 1] = i2; top_w[tok * 2 + 1] = p2;
        atomicAdd(&hist[i1], 1);
        atomicAdd(&hist[i2], 1);
    }
    __syncthreads();
    if (tid < NE) atomicAdd(&counts[tid], hist[tid]);
}

// ---------------- K6: tiny scan — 64-granular (tproj) AND 128-granular (expert) ----------------
__global__ void scan_kernel(const int* __restrict__ counts, int* __restrict__ offsets,
                            int* __restrict__ blk64, int* __restrict__ blk128,
                            int* __restrict__ cursor)
{
    if (threadIdx.x == 0 && blockIdx.x == 0) {
        int o = 0, b6 = 0, b1 = 0;
        for (int e = 0; e < NE; ++e) {
            offsets[e] = o; blk64[e] = b6; blk128[e] = b1; cursor[e] = 0;
            o += counts[e];
            b6 += (counts[e] + 63) >> 6;
            b1 += (counts[e] + 127) >> 7;
        }
        offsets[NE] = o; blk64[NE] = b6; blk128[NE] = b1;
    }
}

// ---------------- K7: build per-expert token lists ----------------
__global__ __launch_bounds__(256) void build_lists_kernel(
    const int* __restrict__ top_i, const float* __restrict__ top_w,
    const int* __restrict__ offsets, int* __restrict__ cursor,
    int* __restrict__ list_tok, float* __restrict__ list_w)
{
    int t = blockIdx.x * 256 + threadIdx.x;
#pragma unroll
    for (int j = 0; j < 2; ++j) {
        int e = top_i[t * 2 + j];
        int pos = atomicAdd(&cursor[e], 1);
        int idx = offsets[e] + pos;
        list_tok[idx] = t;
        list_w[idx] = top_w[t * 2 + j];
    }
}

// ---------------- K8: t = x @ U_e — M=64 (grid ~528, 2/CU; R4-verified geometry) ----------------
__global__ __launch_bounds__(256, 4) void tproj_kernel(
    const u16* __restrict__ xbf, const u16* __restrict__ uT,
    const int* __restrict__ list_tok, const int* __restrict__ offsets,
    const int* __restrict__ blk64, u16* __restrict__ tbf)
{
    __shared__ __align__(16) u16 lds[2 * 6144];
    __shared__ int s_tok[64];
    int mb = blockIdx.x;
    int e = 0;
#pragma unroll
    for (int i = 0; i < NE; ++i) if (mb >= blk64[i + 1]) e = i + 1;
    if (e >= NE) return;
    int mloc = (mb - blk64[e]) * 64;
    int base = offsets[e] + mloc;
    int cnt = offsets[e + 1] - offsets[e];
    int mv = min(64, cnt - mloc);
    int tid = threadIdx.x, lane = tid & 63, w = tid >> 6;
    if (tid < 64) s_tok[tid] = list_tok[base + (tid < mv ? tid : 0)];
    __syncthreads();
    int lrow = lane >> 2;
    int sl = (lane & 3) ^ ((lane >> 3) & 3);
    int rr = lane & 15, hi = lane >> 4;
    int rslot = hi ^ ((rr >> 1) & 3);
    const u16* uE = uT + (size_t)e * RD * HD;

    const u16* gb[3]; char* lp[3];
#pragma unroll
    for (int i = 0; i < 3; ++i) {
        int idx = w + 4 * i;               // 0..11
        if (idx < 4) {
            int row = idx * 16 + lrow;     // token row 0..63
            gb[i] = xbf + (size_t)s_tok[row] * HD + sl * 8;
            lp[i] = (char*)lds + idx * 1024;
        } else {
            int row = (idx - 4) * 16 + lrow;   // U row 0..127
            gb[i] = uE + (size_t)row * HD + sl * 8;
            lp[i] = (char*)lds + 4096 + (idx - 4) * 1024;
        }
    }
    const f32x4 zz = {0.f, 0.f, 0.f, 0.f};
    f32x4 acc[4][2];
#pragma unroll
    for (int im = 0; im < 4; ++im)
#pragma unroll
        for (int in = 0; in < 2; ++in) acc[im][in] = zz;

    auto STAGE = [&](int buf, int t) {
#pragma unroll
        for (int i = 0; i < 3; ++i) gload16(gb[i] + t * 32, lp[i] + buf * 12288);
    };
    auto COMP = [&](int buf, f32x4 (&a)[4][2]) {
        const u16* LA = lds + buf * 6144;
        const u16* LB = LA + 2048;
        bf16x8 af[4], bfv[2];
#pragma unroll
        for (int im = 0; im < 4; ++im) af[im] = *(const bf16x8*)&LA[(im * 16 + rr) * 32 + rslot * 8];
#pragma unroll
        for (int in = 0; in < 2; ++in) bfv[in] = *(const bf16x8*)&LB[(w * 32 + in * 16 + rr) * 32 + rslot * 8];
#pragma unroll
        for (int im = 0; im < 4; ++im)
#pragma unroll
            for (int in = 0; in < 2; ++in)
                a[im][in] = __builtin_amdgcn_mfma_f32_16x16x32_bf16(af[im], bfv[in], a[im][in], 0, 0, 0);
    };

    STAGE(0, 0);
    __syncthreads();
    for (int t = 0; t < 31; ++t) {
        STAGE((t + 1) & 1, t + 1);
        COMP(t & 1, acc);
        __syncthreads();
    }
    COMP(1, acc);

#pragma unroll
    for (int im = 0; im < 4; ++im)
#pragma unroll
        for (int in = 0; in < 2; ++in)
#pragma unroll
            for (int j = 0; j < 4; ++j) {
                int r = im * 16 + hi * 4 + j;
                if (r < mv) {
                    int c = w * 32 + in * 16 + rr;
                    tbf[(size_t)(base + r) * RD + c] = f2bf(acc[im][in][j]);
                }
            }
}

// ---------------- K9: trans GEMM + gate GEMM + highway epilogue (R10 verbatim) ----------------
__global__ __launch_bounds__(256, 3) void expert_kernel(
    const u16* __restrict__ xbf, const u16* __restrict__ wgT,
    const u16* __restrict__ vT, const u16* __restrict__ tbf,
    const float* __restrict__ x, const float* __restrict__ bg,
    const int* __restrict__ list_tok, const float* __restrict__ list_w,
    const int* __restrict__ offsets, const int* __restrict__ blk128,
    float* __restrict__ out)
{
    __shared__ __align__(16) u16 lds[2 * 8192];
    __shared__ int s_tok[128];
    __shared__ float s_w[128];
    int d = blockIdx.x;
    int l = (d >> 8) * 256 + (d & 7) * 32 + ((d & 255) >> 3);
    if (l >= LOGB) return;
    int g = l >> 5, i2d = l & 31;
    int mb = (g >> 1) * 8 + (i2d & 7);
    int ct = (g & 1) * 4 + (i2d >> 3);
    int e = 0;
#pragma unroll
    for (int i = 0; i < NE; ++i) if (mb >= blk128[i + 1]) e = i + 1;
    if (e >= NE) return;
    int mloc = (mb - blk128[e]) * 128;
    int base = offsets[e] + mloc;
    int cnt = offsets[e + 1] - offsets[e];
    int mv = min(128, cnt - mloc);
    int tid = threadIdx.x, lane = tid & 63, w = tid >> 6;
    if (tid < 128) {
        int p = base + (tid < mv ? tid : 0);
        s_tok[tid] = list_tok[p];
        s_w[tid] = (tid < mv) ? list_w[p] : 0.f;
    }
    __syncthreads();
    int lrow = lane >> 2;
    int sl = (lane & 3) ^ ((lane >> 3) & 3);
    int rr = lane & 15, hi = lane >> 4;
    int rslot = hi ^ ((rr >> 1) & 3);
    int wr = w >> 1, wc = w & 1;

    const u16* wgE = wgT + (size_t)e * HD * HD + (size_t)(ct * 128) * HD;
    const u16* vE  = vT  + (size_t)e * HD * RD + (size_t)(ct * 128) * RD;

    char* lp[4];
    const u16* gbT[4]; const u16* gbG[4];
#pragma unroll
    for (int i = 0; i < 4; ++i) {
        int idx = w + 4 * i;
        if (idx < 8) {
            int row = idx * 16 + lrow;
            lp[i]  = (char*)lds + idx * 1024;
            gbT[i] = tbf + (size_t)(base + (row < mv ? row : 0)) * RD + sl * 8;
            gbG[i] = xbf + (size_t)s_tok[row] * HD + sl * 8;
        } else {
            int row = (idx - 8) * 16 + lrow;
            lp[i]  = (char*)lds + 8192 + (idx - 8) * 1024;
            gbT[i] = vE  + (size_t)row * RD + sl * 8;
            gbG[i] = wgE + (size_t)row * HD + sl * 8;
        }
    }

    auto STAGE = [&](int buf, int t, const u16* const (&gb)[4]) {
#pragma unroll
        for (int i = 0; i < 4; ++i) gload16(gb[i] + t * 32, lp[i] + buf * 16384);
    };
    auto COMP = [&](int buf, f32x4 (&a)[4][4]) {
        const u16* LA = lds + buf * 8192;
        const u16* LB = LA + 4096;
        bf16x8 af[4], bfv[4];
#pragma unroll
        for (int im = 0; im < 4; ++im) af[im] = *(const bf16x8*)&LA[(wr * 64 + im * 16 + rr) * 32 + rslot * 8];
#pragma unroll
        for (int in = 0; in < 4; ++in) bfv[in] = *(const bf16x8*)&LB[(wc * 64 + in * 16 + rr) * 32 + rslot * 8];
#pragma unroll
        for (int im = 0; im < 4; ++im)
#pragma unroll
            for (int in = 0; in < 4; ++in)
                a[im][in] = __builtin_amdgcn_mfma_f32_16x16x32_bf16(af[im], bfv[in], a[im][in], 0, 0, 0);
    };

    const f32x4 zz = {0.f, 0.f, 0.f, 0.f};
    f32x4 accT[4][4];
#pragma unroll
    for (int im = 0; im < 4; ++im)
#pragma unroll
        for (int in = 0; in < 4; ++in) accT[im][in] = zz;

    STAGE(0, 0, gbT);
    __syncthreads();
#pragma unroll
    for (int s = 0; s < 4; ++s) {
        if (s < 3) STAGE((s + 1) & 1, s + 1, gbT);
        else       STAGE(0, 0, gbG);
        COMP(s & 1, accT);
        __syncthreads();
    }

    __half2 tpk[4][4][2];
#pragma unroll
    for (int im = 0; im < 4; ++im)
#pragma unroll
        for (int in = 0; in < 4; ++in) {
            tpk[im][in][0] = __floats2half2_rn(accT[im][in][0], accT[im][in][1]);
            tpk[im][in][1] = __floats2half2_rn(accT[im][in][2], accT[im][in][3]);
        }

    f32x4 accG[4][4];
#pragma unroll
    for (int im = 0; im < 4; ++im)
#pragma unroll
        for (int in = 0; in < 4; ++in) accG[im][in] = zz;

    for (int t = 0; t < 31; ++t) {
        STAGE((t + 1) & 1, t + 1, gbG);
        COMP(t & 1, accG);
        __syncthreads();
    }
    COMP(1, accG);

    float bgv[4];
#pragma unroll
    for (int in = 0; in < 4; ++in)
        bgv[in] = bg[e * HD + ct * 128 + wc * 64 + in * 16 + rr];

#pragma unroll
    for (int im = 0; im < 4; ++im)
#pragma unroll
        for (int j = 0; j < 4; ++j) {
            int r = wr * 64 + im * 16 + hi * 4 + j;
            if (r < mv) {
                int tok = s_tok[r];
                float wgt = s_w[r];
                size_t rowoff = (size_t)tok * HD;
#pragma unroll
                for (int in = 0; in < 4; ++in) {
                    int c = ct * 128 + wc * 64 + in * 16 + rr;
                    float gp = accG[im][in][j] + bgv[in];
                    float sg = 1.f / (1.f + __expf(-gp));
                    float2 tq = __half22float2(tpk[im][in][j >> 1]);
                    float tr = (j & 1) ? tq.y : tq.x;
                    float xv = x[rowoff + c];
                    float yv = sg * tr + (1.f - sg) * xv;
                    atomicAdd(&out[rowoff + c], wgt * yv);
                }
            }
        }
}

extern "C" void kernel_launch(void* const* d_in, const int* in_sizes, int n_in,
                              void* d_out, int out_size, void* d_ws, size_t ws_size,
                              hipStream_t stream)
{
    const float* x   = (const float*)d_in[0];
    const float* Wd  = (const float*)d_in[1];
    const float* bd  = (const float*)d_in[2];
    const float* cen = (const float*)d_in[3];
    const float* Wg  = (const float*)d_in[4];
    const float* bg  = (const float*)d_in[5];
    const float* U   = (const float*)d_in[6];
    const float* V   = (const float*)d_in[7];
    float* out = (float*)d_out;

    char* ws = (char*)d_ws;
    size_t off = 0;
    auto alloc = [&](size_t bytes) { size_t o = off; off = (off + bytes + 255) & ~(size_t)255; return o; };
    float* dT        = (float*)(ws + alloc((size_t)NTOK * CD * 4));
    float* cn        = (float*)(ws + alloc((size_t)NE * CD * 4));
    float* sncn      = (float*)(ws + alloc(NE * 4));
    int*   top_i     = (int*)(ws + alloc((size_t)NTOK * 2 * 4));
    float* top_w     = (float*)(ws + alloc((size_t)NTOK * 2 * 4));
    int*   counts    = (int*)(ws + alloc(NE * 4));
    int*   offsets   = (int*)(ws + alloc((NE + 1) * 4));
    int*   blk64     = (int*)(ws + alloc((NE + 1) * 4));
    int*   blk128    = (int*)(ws + alloc((NE + 1) * 4));
    int*   cursor    = (int*)(ws + alloc(NE * 4));
    int*   list_tok  = (int*)(ws + alloc((size_t)NTOK * 2 * 4));
    float* list_w    = (float*)(ws + alloc((size_t)NTOK * 2 * 4));
    u16*   xbf       = (u16*)(ws + alloc((size_t)NTOK * HD * 2));
    u16*   xlo       = (u16*)(ws + alloc((size_t)NTOK * HD * 2));
    u16*   wdh       = (u16*)(ws + alloc((size_t)CD * HD * 2));
    u16*   wdl       = (u16*)(ws + alloc((size_t)CD * HD * 2));
    u16*   wgT       = (u16*)(ws + alloc((size_t)NE * HD * HD * 2));
    u16*   uT        = (u16*)(ws + alloc((size_t)NE * RD * HD * 2));
    u16*   vT        = (u16*)(ws + alloc((size_t)NE * RD * HD * 2));
    u16*   tbf       = (u16*)(ws + alloc(((size_t)NTOK * 2 + 128) * RD * 2));

    hipMemsetAsync(out, 0, (size_t)out_size * 4, stream);

    centroid_norm_kernel<<<NE, 64, 0, stream>>>(cen, cn, sncn, counts);
    cvt_split_kernel<<<(NTOK * HD / 4 + 255) / 256, 256, 0, stream>>>(x, xbf, xlo, NTOK * HD / 4);
    transpose_cvt_split_kernel<<<dim3(CD / 32, HD / 32), 256, 0, stream>>>(Wd, wdh, wdl, HD, CD);
    router_mfma_kernel<<<(NTOK / 64) * 2, 256, 0, stream>>>(xbf, xlo, wdh, wdl, bd, dT);
    router_score_kernel<<<NTOK / 64, 256, 0, stream>>>(dT, cn, sncn, top_i, top_w, counts);
    scan_kernel<<<1, 64, 0, stream>>>(counts, offsets, blk64, blk128, cursor);
    build_lists_kernel<<<NTOK / 256, 256, 0, stream>>>(top_i, top_w, offsets, cursor, list_tok, list_w);

    transpose_cvt_kernel<<<dim3(HD / 32, HD / 32, NE), 256, 0, stream>>>(Wg, wgT, HD, HD);
    transpose_cvt_kernel<<<dim3(RD / 32, HD / 32, NE), 256, 0, stream>>>(U, uT, HD, RD);
    transpose_cvt_kernel<<<dim3(HD / 32, RD / 32, NE), 256, 0, stream>>>(V, vT, RD, HD);

    tproj_kernel<<<MB64, 256, 0, stream>>>(xbf, uT, list_tok, offsets, blk64, tbf);
    expert_kernel<<<EGRID, 256, 0, stream>>>(xbf, wgT, vT, tbf, x, bg,
                                             list_tok, list_w, offsets, blk128, out);
}